// Round 7
// baseline (112.035 us; speedup 1.0000x reference)
//
#include <hip/hip_runtime.h>

// 8-qubit QCNN via a Chebyshev-grid surrogate, 2-kernel pipeline.
// Features f_j depend ONLY on (theta, phi); bandwidth <= 32 rad over [0,1)
// => a 32x32 Chebyshev-node grid interpolates to ~1e-6 (verified: absmax ~0
// in round 6 with the equivalent DCT form).
//   K_A: simulate base state + one branch per wave on the 32x32 grid
//        (3072 waves) -> feat[6][1024].
//   K_B: barycentric Lagrange eval of the 6 features per batch element
//        (same interpolant as the DCT fit, no fit kernel needed) + MLP.
// Simulation math identical to rounds 5/6 (ref-checked, absmax ~ 0).

#define PI_F 3.14159265358979323846f
constexpr int NCH  = 32;
constexpr int NPTS = NCH * NCH;  // 1024 grid points

struct cplx { float re, im; };
struct Gate { cplx u00, u01, u10, u11; };

// ---------------- compile-time GF(2) linear algebra ----------------
struct M8 { unsigned r[8]; };  // logical bit p of i = parity(r[p] & i)

constexpr M8 midentity() {
    M8 F{};
    for (int i = 0; i < 8; ++i) F.r[i] = 1u << i;
    return F;
}

constexpr M8 ring_update(M8 F) {
    const int pc[8] = {7, 6, 5, 4, 3, 2, 1, 0};
    const int pt[8] = {6, 5, 4, 3, 2, 1, 0, 7};
    for (int g = 0; g < 8; ++g) F.r[pt[g]] ^= F.r[pc[g]];
    return F;
}

constexpr M8 minv(M8 F) {
    unsigned a[8] = {}, b[8] = {};
    for (int i = 0; i < 8; ++i) { a[i] = F.r[i]; b[i] = 1u << i; }
    for (int c = 0; c < 8; ++c) {
        int p = c;
        while (((a[p] >> c) & 1u) == 0u) ++p;
        unsigned ta = a[p]; a[p] = a[c]; a[c] = ta;
        unsigned tb = b[p]; b[p] = b[c]; b[c] = tb;
        for (int rr = 0; rr < 8; ++rr)
            if (rr != c && ((a[rr] >> c) & 1u)) { a[rr] ^= a[c]; b[rr] ^= b[c]; }
    }
    M8 R{};
    for (int i = 0; i < 8; ++i) R.r[i] = b[i];
    return R;
}

constexpr unsigned mcol(M8 F, int p) {
    unsigned m = 0;
    for (int q = 0; q < 8; ++q) m |= ((F.r[q] >> p) & 1u) << q;
    return m;
}

constexpr M8 F1 = ring_update(midentity());
constexpr M8 F2 = ring_update(F1);
constexpr M8 F3 = ring_update(F2);
constexpr M8 F4 = ring_update(F3);
constexpr M8 F1i = minv(F1);
constexpr M8 F2i = minv(F2);
constexpr M8 F3i = minv(F3);
constexpr M8 F4i = minv(F4);

// ---------------- device helpers ----------------
__device__ __forceinline__ float shflx(float v, int m) { return __shfl_xor(v, m, 64); }

__device__ __forceinline__ cplx cfma2(cplx u, cplx a, cplx v, cplx b) {
    cplx r;
    r.re = u.re * a.re - u.im * a.im + v.re * b.re - v.im * b.im;
    r.im = u.re * a.im + u.im * a.re + v.re * b.im + v.im * b.re;
    return r;
}

template <unsigned X>
__device__ __forceinline__ void partner(const cplx a[4], cplx o[4]) {
    constexpr unsigned kx = X & 3u, lx = X >> 2;
    #pragma unroll
    for (int k = 0; k < 4; ++k) {
        const int ks = k ^ (int)kx;
        if constexpr (lx != 0) {
            o[k].re = shflx(a[ks].re, (int)lx);
            o[k].im = shflx(a[ks].im, (int)lx);
        } else {
            o[k] = a[ks];
        }
    }
}

template <unsigned X, unsigned R>
__device__ __forceinline__ void gate_ry(cplx a[4], float c, float s, int lane) {
    cplx o[4];
    partner<X>(a, o);
    const bool hl = (__popc(lane & (int)(R >> 2)) & 1) != 0;
    const float v = hl ? s : -s;
    #pragma unroll
    for (int k = 0; k < 4; ++k) {
        const int kp = __builtin_popcount((unsigned)k & (R & 3u)) & 1;
        const float sg = kp ? -v : v;
        a[k].re = c * a[k].re + sg * o[k].re;
        a[k].im = c * a[k].im + sg * o[k].im;
    }
}

template <unsigned X, unsigned R>
__device__ __forceinline__ void gate_u3(cplx a[4], const Gate& g, int lane) {
    cplx o[4];
    partner<X>(a, o);
    const bool hl = (__popc(lane & (int)(R >> 2)) & 1) != 0;
    cplx ca0, cb0, ca1, cb1;
    ca0.re = hl ? g.u11.re : g.u00.re;  ca0.im = hl ? g.u11.im : g.u00.im;
    cb0.re = hl ? g.u10.re : g.u01.re;  cb0.im = hl ? g.u10.im : g.u01.im;
    ca1.re = hl ? g.u00.re : g.u11.re;  ca1.im = hl ? g.u00.im : g.u11.im;
    cb1.re = hl ? g.u01.re : g.u10.re;  cb1.im = hl ? g.u01.im : g.u10.im;
    #pragma unroll
    for (int k = 0; k < 4; ++k) {
        const int kp = __builtin_popcount((unsigned)k & (R & 3u)) & 1;
        const cplx ca = kp ? ca1 : ca0;
        const cplx cb = kp ? cb1 : cb0;
        a[k] = cfma2(ca, a[k], cb, o[k]);
    }
}

template <unsigned X, unsigned RC>
__device__ __forceinline__ void gate_crx(cplx a[4], float c, float s, int lane) {
    cplx o[4];
    partner<X>(a, o);
    const bool cl = (__popc(lane & (int)(RC >> 2)) & 1) != 0;
    const float ce0 = cl ? c : 1.f, se0 = cl ? s : 0.f;
    const float ce1 = cl ? 1.f : c, se1 = cl ? 0.f : s;
    #pragma unroll
    for (int k = 0; k < 4; ++k) {
        const int kp = __builtin_popcount((unsigned)k & (RC & 3u)) & 1;
        const float ce = kp ? ce1 : ce0, se = kp ? se1 : se0;
        cplx n;
        n.re = ce * a[k].re + se * o[k].im;
        n.im = ce * a[k].im - se * o[k].re;
        a[k] = n;
    }
}

template <unsigned X, unsigned R, unsigned RC>
__device__ __forceinline__ void gate_cry(cplx a[4], float c, float s, int lane) {
    cplx o[4];
    partner<X>(a, o);
    const bool cl = (__popc(lane & (int)(RC >> 2)) & 1) != 0;
    const bool hl = (__popc(lane & (int)(R >> 2)) & 1) != 0;
    #pragma unroll
    for (int k = 0; k < 4; ++k) {
        const bool ctrl = cl ^ ((__builtin_popcount((unsigned)k & (RC & 3u)) & 1) != 0);
        const bool hi   = hl ^ ((__builtin_popcount((unsigned)k & (R & 3u)) & 1) != 0);
        const float ce = ctrl ? c : 1.f;
        const float sg = hi ? s : -s;
        const float se = ctrl ? sg : 0.f;
        cplx n;
        n.re = ce * a[k].re + se * o[k].re;
        n.im = ce * a[k].im + se * o[k].im;
        a[k] = n;
    }
}

template <unsigned R, unsigned RC>
__device__ __forceinline__ void gate_crz(cplx a[4], float c, float s, int lane) {
    const bool cl = (__popc(lane & (int)(RC >> 2)) & 1) != 0;
    const bool hl = (__popc(lane & (int)(R >> 2)) & 1) != 0;
    #pragma unroll
    for (int k = 0; k < 4; ++k) {
        const bool ctrl = cl ^ ((__builtin_popcount((unsigned)k & (RC & 3u)) & 1) != 0);
        const bool hi   = hl ^ ((__builtin_popcount((unsigned)k & (R & 3u)) & 1) != 0);
        const float fr = ctrl ? c : 1.f;
        const float sg = hi ? s : -s;
        const float fi = ctrl ? sg : 0.f;
        cplx n;
        n.re = fr * a[k].re - fi * a[k].im;
        n.im = fr * a[k].im + fi * a[k].re;
        a[k] = n;
    }
}

template <int C>
__device__ __forceinline__ void cycle_ry(cplx a[4], float c, float s, int lane) {
    constexpr M8 F  = (C == 1) ? F1 : (C == 2) ? F2 : F3;
    constexpr M8 Fi = (C == 1) ? F1i : (C == 2) ? F2i : F3i;
    gate_ry<mcol(Fi, 7), F.r[7]>(a, c, s, lane);
    gate_ry<mcol(Fi, 6), F.r[6]>(a, c, s, lane);
    gate_ry<mcol(Fi, 5), F.r[5]>(a, c, s, lane);
    gate_ry<mcol(Fi, 4), F.r[4]>(a, c, s, lane);
    gate_ry<mcol(Fi, 3), F.r[3]>(a, c, s, lane);
    gate_ry<mcol(Fi, 2), F.r[2]>(a, c, s, lane);
    gate_ry<mcol(Fi, 1), F.r[1]>(a, c, s, lane);
    gate_ry<mcol(Fi, 0), F.r[0]>(a, c, s, lane);
}

template <int C>
__device__ __forceinline__ void cycle_diag(cplx a[4], float phw, int lane) {
    constexpr M8 F = (C == 1) ? F1 : (C == 2) ? F2 : F3;
    int hp[8];
    #pragma unroll
    for (int p = 0; p < 8; ++p) hp[p] = __popc(lane & (int)(F.r[p] >> 2)) & 1;
    #pragma unroll
    for (int k = 0; k < 4; ++k) {
        int n = 0;
        #pragma unroll
        for (int p = 0; p < 8; ++p) {
            const int kb = __builtin_popcount(F.r[p] & 3u & (unsigned)k) & 1;
            n += kb ? (1 - hp[p]) : hp[p];
        }
        float sn, cn;
        __sincosf(phw * (float)(n - 4), &sn, &cn);
        cplx v;
        v.re = cn * a[k].re - sn * a[k].im;
        v.im = cn * a[k].im + sn * a[k].re;
        a[k] = v;
    }
}

struct BranchG { float rc[10], rs[10]; Gate u[6]; };

template <int KIND, int PC, int PT>
__device__ __forceinline__ void crot(cplx a[4], float c, float s, int lane) {
    constexpr unsigned X = mcol(F4i, PT), R = F4.r[PT], RC = F4.r[PC];
    if constexpr (KIND == 0)      gate_crx<X, RC>(a, c, s, lane);
    else if constexpr (KIND == 1) gate_cry<X, R, RC>(a, c, s, lane);
    else                          gate_crz<R, RC>(a, c, s, lane);
}

template <int KIND>
__device__ __forceinline__ void run_branch(const BranchG& G, cplx a[4],
                                           int lane, float& o3, float& o7) {
    crot<KIND, 7, 6>(a, G.rc[0], G.rs[0], lane);
    crot<KIND, 5, 4>(a, G.rc[1], G.rs[1], lane);
    crot<KIND, 3, 2>(a, G.rc[2], G.rs[2], lane);
    crot<KIND, 1, 0>(a, G.rc[3], G.rs[3], lane);
    crot<KIND, 6, 5>(a, G.rc[4], G.rs[4], lane);
    crot<KIND, 4, 3>(a, G.rc[5], G.rs[5], lane);
    crot<KIND, 2, 1>(a, G.rc[6], G.rs[6], lane);
    gate_u3<mcol(F4i, 6), F4.r[6]>(a, G.u[0], lane);
    gate_u3<mcol(F4i, 4), F4.r[4]>(a, G.u[1], lane);
    gate_u3<mcol(F4i, 2), F4.r[2]>(a, G.u[2], lane);
    gate_u3<mcol(F4i, 0), F4.r[0]>(a, G.u[3], lane);
    crot<KIND, 6, 4>(a, G.rc[7], G.rs[7], lane);
    crot<KIND, 2, 0>(a, G.rc[8], G.rs[8], lane);
    crot<KIND, 4, 2>(a, G.rc[9], G.rs[9], lane);
    gate_u3<mcol(F4i, 4), F4.r[4]>(a, G.u[4], lane);
    gate_u3<mcol(F4i, 0), F4.r[0]>(a, G.u[5], lane);

    constexpr unsigned R3 = F4.r[4], R7 = F4.r[0];
    const bool h3 = (__popc(lane & (int)(R3 >> 2)) & 1) != 0;
    const bool h7 = (__popc(lane & (int)(R7 >> 2)) & 1) != 0;
    float p3 = 0.f, p7 = 0.f;
    #pragma unroll
    for (int k = 0; k < 4; ++k) {
        const float m = a[k].re * a[k].re + a[k].im * a[k].im;
        const bool s3 = h3 ^ ((__builtin_popcount((unsigned)k & (R3 & 3u)) & 1) != 0);
        const bool s7 = h7 ^ ((__builtin_popcount((unsigned)k & (R7 & 3u)) & 1) != 0);
        p3 += s3 ? -m : m;
        p7 += s7 ? -m : m;
    }
    #pragma unroll
    for (int off = 32; off >= 1; off >>= 1) {
        p3 += shflx(p3, off);
        p7 += shflx(p7, off);
    }
    o3 = p3;
    o7 = p7;
}

// ---------------- K_A: fused base + one branch per wave on the grid ----------------
// Wave W in [0, 3072): branch = W/1024, grid point p = W%1024.
__global__ void __launch_bounds__(256) k_grid(
    float* __restrict__ feat,
    const float* __restrict__ ax, const float* __restrict__ ay, const float* __restrict__ az,
    const float* __restrict__ u3x, const float* __restrict__ u3y, const float* __restrict__ u3z) {
    __shared__ BranchG gb[3];
    const int t = threadIdx.x;
    if (t < 30) {
        const int br = t / 10, i = t - br * 10;
        const float* ang = (br == 0) ? ax : (br == 1) ? ay : az;
        float s, c;
        __sincosf(0.5f * ang[i], &s, &c);
        gb[br].rc[i] = c;
        gb[br].rs[i] = s;
    } else if (t >= 32 && t < 50) {
        const int idx = t - 32, br = idx / 6, row = idx - br * 6;
        const float* up = (br == 0) ? u3x : (br == 1) ? u3y : u3z;
        const float th = up[row * 3 + 0], ph = up[row * 3 + 1], lm = up[row * 3 + 2];
        float sth, cth; __sincosf(0.5f * th, &sth, &cth);
        float sph, cph; __sincosf(ph, &sph, &cph);
        float slm, clm; __sincosf(lm, &slm, &clm);
        float spl, cpl; __sincosf(ph + lm, &spl, &cpl);
        Gate G;
        G.u00 = {cth, 0.f};
        G.u01 = {-clm * sth, -slm * sth};
        G.u10 = {cph * sth, sph * sth};
        G.u11 = {cpl * cth, spl * cth};
        gb[br].u[row] = G;
    }
    __syncthreads();

    const int W    = blockIdx.x * 4 + (t >> 6);   // 0..3071
    const int br   = W >> 10;
    const int p    = W & 1023;
    const int lane = t & 63;
    const int it = p >> 5, ip = p & 31;
    const float xt = cosf(PI_F * (float)(2 * it + 1) / (2.0f * NCH));
    const float xp = cosf(PI_F * (float)(2 * ip + 1) / (2.0f * NCH));
    const float thv = 0.5f * (xt + 1.f), phv = 0.5f * (xp + 1.f);

    float s, c, sp, cp;
    __sincosf(0.5f * thv, &s, &c);
    __sincosf(0.5f * phv, &sp, &cp);

    // base state: closed-form cycle 1, then relabeled cycles 2-4
    cplx a[4];
    {
        float f = 1.f;
        #pragma unroll
        for (int bb = 0; bb < 6; ++bb) f *= ((lane >> bb) & 1) ? s : c;
        const int pl = __popc(lane);
        float e0s, e0c;
        __sincosf(phv * (float)(pl - 4), &e0s, &e0c);
        const float e1c = cp * cp - sp * sp;
        const float e1s = 2.f * sp * cp;
        cplx e0{e0c, e0s};
        cplx e1{e0.re * e1c - e0.im * e1s, e0.re * e1s + e0.im * e1c};
        cplx e2{e1.re * e1c - e1.im * e1s, e1.re * e1s + e1.im * e1c};
        const float cc = c * c, cs = c * s, ss = s * s;
        a[0] = {f * cc * e0.re, f * cc * e0.im};
        a[1] = {f * cs * e1.re, f * cs * e1.im};
        a[2] = {f * cs * e1.re, f * cs * e1.im};
        a[3] = {f * ss * e2.re, f * ss * e2.im};
    }
    cycle_ry<1>(a, c, s, lane);  cycle_diag<1>(a, phv, lane);
    cycle_ry<2>(a, c, s, lane);  cycle_diag<2>(a, phv, lane);
    cycle_ry<3>(a, c, s, lane);  cycle_diag<3>(a, phv, lane);

    float o3, o7;
    if (br == 0)      run_branch<0>(gb[0], a, lane, o3, o7);
    else if (br == 1) run_branch<1>(gb[1], a, lane, o3, o7);
    else              run_branch<2>(gb[2], a, lane, o3, o7);

    if (lane == 0) {
        feat[(br * 2 + 0) * NPTS + p] = o3;
        feat[(br * 2 + 1) * NPTS + p] = o7;
    }
}

// ---------------- K_B: barycentric Lagrange eval + MLP ----------------
// Block = 384 threads = 6 waves; block handles 64 elements (lane = element),
// wave w evaluates feature w (coefficient reads wave-uniform -> scalar).
__global__ void __launch_bounds__(384) k_eval(
    const float* __restrict__ theta, const float* __restrict__ phi,
    const float* __restrict__ feat,
    const float* __restrict__ W1, const float* __restrict__ b1,
    const float* __restrict__ W2, const float* __restrict__ b2,
    float* __restrict__ out, int B) {
    __shared__ float fsh[6][64];
    const int t = threadIdx.x, wv = t >> 6, lane = t & 63;
    const int e = blockIdx.x * 64 + lane;
    const bool valid = (e < B);

    const float xt = valid ? (2.f * theta[e] - 1.f) : 0.f;
    const float xp = valid ? (2.f * phi[e]   - 1.f) : 0.f;

    // Barycentric weights for Chebyshev-1 nodes: w_i = (-1)^i sin((2i+1)pi/2N).
    float u[NCH], v[NCH];
    float su = 0.f, sv = 0.f;
    #pragma unroll
    for (int i = 0; i < NCH; ++i) {
        const float ang = (float)(2 * i + 1) * (PI_F / (2.0f * NCH));
        float sa, ca;
        __sincosf(ang, &sa, &ca);
        const float wi = (i & 1) ? -sa : sa;
        float dt = xt - ca;
        float dp = xp - ca;
        dt = (dt == 0.f) ? 1e-18f : dt;   // exact node hit -> term dominates
        dp = (dp == 0.f) ? 1e-18f : dp;
        u[i] = wi / dt;
        v[i] = wi / dp;
        su += u[i];
        sv += v[i];
    }
    const float inv = 1.f / (su * sv);

    // f = (u^T F v) * inv  for this wave's feature.
    const float* F = feat + wv * NPTS;
    float acc = 0.f;
    #pragma unroll 4
    for (int i = 0; i < NCH; ++i) {
        float row = 0.f;
        #pragma unroll
        for (int j = 0; j < NCH; ++j) row = fmaf(F[i * NCH + j], v[j], row);
        acc = fmaf(u[i], row, acc);
    }
    fsh[wv][lane] = acc * inv;
    __syncthreads();

    if (wv == 0 && valid) {
        float fv[6];
        #pragma unroll
        for (int f = 0; f < 6; ++f) fv[f] = fsh[f][lane];
        float o = b2[0];
        #pragma unroll
        for (int j = 0; j < 12; ++j) {
            float h = b1[j];
            #pragma unroll
            for (int k = 0; k < 6; ++k) h = fmaf(W1[j * 6 + k], fv[k], h);
            const float ex = __expf(2.f * h);
            o = fmaf(W2[j], (ex - 1.f) / (ex + 1.f), o);  // tanh
        }
        out[e] = 1.f / (1.f + __expf(-o));
    }
}

extern "C" void kernel_launch(void* const* d_in, const int* in_sizes, int n_in,
                              void* d_out, int out_size, void* d_ws, size_t ws_size,
                              hipStream_t stream) {
    const float* theta = (const float*)d_in[0];
    const float* phi   = (const float*)d_in[1];
    const float* ax    = (const float*)d_in[2];
    const float* ay    = (const float*)d_in[3];
    const float* az    = (const float*)d_in[4];
    const float* u3x   = (const float*)d_in[5];
    const float* u3y   = (const float*)d_in[6];
    const float* u3z   = (const float*)d_in[7];
    const float* W1    = (const float*)d_in[8];
    const float* b1    = (const float*)d_in[9];
    const float* W2    = (const float*)d_in[10];
    const float* b2    = (const float*)d_in[11];
    const int B = in_sizes[0];

    float* feat = (float*)d_ws;  // 6 * 1024 floats = 24 KB

    k_grid<<<3 * NPTS / 4, 256, 0, stream>>>(feat, ax, ay, az, u3x, u3y, u3z);
    k_eval<<<(B + 63) / 64, 384, 0, stream>>>(theta, phi, feat,
                                              W1, b1, W2, b2, (float*)d_out, B);
}

// Round 8
// 107.390 us; speedup vs baseline: 1.0432x; 1.0432x over previous
//
#include <hip/hip_runtime.h>

// 8-qubit QCNN via a Chebyshev-grid surrogate, 2-kernel pipeline.
//   K_A: simulate base state + one branch per wave on the 32x32 Chebyshev
//        grid (3072 waves) -> feat[6][1024].   (unchanged from round 7)
//   K_B: barycentric Lagrange eval, 8-way row-octant split per block:
//        512 threads = 8 waves per 64 batch elements; wave w computes rows
//        [4w,4w+4) partials for all 6 features, LDS reduce, wave 0 MLP.
// Simulation math identical to rounds 5-7 (ref-checked, absmax ~ 0).

#define PI_F 3.14159265358979323846f
constexpr int NCH  = 32;
constexpr int NPTS = NCH * NCH;  // 1024 grid points

struct cplx { float re, im; };
struct Gate { cplx u00, u01, u10, u11; };

// ---------------- compile-time GF(2) linear algebra ----------------
struct M8 { unsigned r[8]; };  // logical bit p of i = parity(r[p] & i)

constexpr M8 midentity() {
    M8 F{};
    for (int i = 0; i < 8; ++i) F.r[i] = 1u << i;
    return F;
}

constexpr M8 ring_update(M8 F) {
    const int pc[8] = {7, 6, 5, 4, 3, 2, 1, 0};
    const int pt[8] = {6, 5, 4, 3, 2, 1, 0, 7};
    for (int g = 0; g < 8; ++g) F.r[pt[g]] ^= F.r[pc[g]];
    return F;
}

constexpr M8 minv(M8 F) {
    unsigned a[8] = {}, b[8] = {};
    for (int i = 0; i < 8; ++i) { a[i] = F.r[i]; b[i] = 1u << i; }
    for (int c = 0; c < 8; ++c) {
        int p = c;
        while (((a[p] >> c) & 1u) == 0u) ++p;
        unsigned ta = a[p]; a[p] = a[c]; a[c] = ta;
        unsigned tb = b[p]; b[p] = b[c]; b[c] = tb;
        for (int rr = 0; rr < 8; ++rr)
            if (rr != c && ((a[rr] >> c) & 1u)) { a[rr] ^= a[c]; b[rr] ^= b[c]; }
    }
    M8 R{};
    for (int i = 0; i < 8; ++i) R.r[i] = b[i];
    return R;
}

constexpr unsigned mcol(M8 F, int p) {
    unsigned m = 0;
    for (int q = 0; q < 8; ++q) m |= ((F.r[q] >> p) & 1u) << q;
    return m;
}

constexpr M8 F1 = ring_update(midentity());
constexpr M8 F2 = ring_update(F1);
constexpr M8 F3 = ring_update(F2);
constexpr M8 F4 = ring_update(F3);
constexpr M8 F1i = minv(F1);
constexpr M8 F2i = minv(F2);
constexpr M8 F3i = minv(F3);
constexpr M8 F4i = minv(F4);

// ---------------- device helpers ----------------
__device__ __forceinline__ float shflx(float v, int m) { return __shfl_xor(v, m, 64); }

__device__ __forceinline__ cplx cfma2(cplx u, cplx a, cplx v, cplx b) {
    cplx r;
    r.re = u.re * a.re - u.im * a.im + v.re * b.re - v.im * b.im;
    r.im = u.re * a.im + u.im * a.re + v.re * b.im + v.im * b.re;
    return r;
}

template <unsigned X>
__device__ __forceinline__ void partner(const cplx a[4], cplx o[4]) {
    constexpr unsigned kx = X & 3u, lx = X >> 2;
    #pragma unroll
    for (int k = 0; k < 4; ++k) {
        const int ks = k ^ (int)kx;
        if constexpr (lx != 0) {
            o[k].re = shflx(a[ks].re, (int)lx);
            o[k].im = shflx(a[ks].im, (int)lx);
        } else {
            o[k] = a[ks];
        }
    }
}

template <unsigned X, unsigned R>
__device__ __forceinline__ void gate_ry(cplx a[4], float c, float s, int lane) {
    cplx o[4];
    partner<X>(a, o);
    const bool hl = (__popc(lane & (int)(R >> 2)) & 1) != 0;
    const float v = hl ? s : -s;
    #pragma unroll
    for (int k = 0; k < 4; ++k) {
        const int kp = __builtin_popcount((unsigned)k & (R & 3u)) & 1;
        const float sg = kp ? -v : v;
        a[k].re = c * a[k].re + sg * o[k].re;
        a[k].im = c * a[k].im + sg * o[k].im;
    }
}

template <unsigned X, unsigned R>
__device__ __forceinline__ void gate_u3(cplx a[4], const Gate& g, int lane) {
    cplx o[4];
    partner<X>(a, o);
    const bool hl = (__popc(lane & (int)(R >> 2)) & 1) != 0;
    cplx ca0, cb0, ca1, cb1;
    ca0.re = hl ? g.u11.re : g.u00.re;  ca0.im = hl ? g.u11.im : g.u00.im;
    cb0.re = hl ? g.u10.re : g.u01.re;  cb0.im = hl ? g.u10.im : g.u01.im;
    ca1.re = hl ? g.u00.re : g.u11.re;  ca1.im = hl ? g.u00.im : g.u11.im;
    cb1.re = hl ? g.u01.re : g.u10.re;  cb1.im = hl ? g.u01.im : g.u10.im;
    #pragma unroll
    for (int k = 0; k < 4; ++k) {
        const int kp = __builtin_popcount((unsigned)k & (R & 3u)) & 1;
        const cplx ca = kp ? ca1 : ca0;
        const cplx cb = kp ? cb1 : cb0;
        a[k] = cfma2(ca, a[k], cb, o[k]);
    }
}

template <unsigned X, unsigned RC>
__device__ __forceinline__ void gate_crx(cplx a[4], float c, float s, int lane) {
    cplx o[4];
    partner<X>(a, o);
    const bool cl = (__popc(lane & (int)(RC >> 2)) & 1) != 0;
    const float ce0 = cl ? c : 1.f, se0 = cl ? s : 0.f;
    const float ce1 = cl ? 1.f : c, se1 = cl ? 0.f : s;
    #pragma unroll
    for (int k = 0; k < 4; ++k) {
        const int kp = __builtin_popcount((unsigned)k & (RC & 3u)) & 1;
        const float ce = kp ? ce1 : ce0, se = kp ? se1 : se0;
        cplx n;
        n.re = ce * a[k].re + se * o[k].im;
        n.im = ce * a[k].im - se * o[k].re;
        a[k] = n;
    }
}

template <unsigned X, unsigned R, unsigned RC>
__device__ __forceinline__ void gate_cry(cplx a[4], float c, float s, int lane) {
    cplx o[4];
    partner<X>(a, o);
    const bool cl = (__popc(lane & (int)(RC >> 2)) & 1) != 0;
    const bool hl = (__popc(lane & (int)(R >> 2)) & 1) != 0;
    #pragma unroll
    for (int k = 0; k < 4; ++k) {
        const bool ctrl = cl ^ ((__builtin_popcount((unsigned)k & (RC & 3u)) & 1) != 0);
        const bool hi   = hl ^ ((__builtin_popcount((unsigned)k & (R & 3u)) & 1) != 0);
        const float ce = ctrl ? c : 1.f;
        const float sg = hi ? s : -s;
        const float se = ctrl ? sg : 0.f;
        cplx n;
        n.re = ce * a[k].re + se * o[k].re;
        n.im = ce * a[k].im + se * o[k].im;
        a[k] = n;
    }
}

template <unsigned R, unsigned RC>
__device__ __forceinline__ void gate_crz(cplx a[4], float c, float s, int lane) {
    const bool cl = (__popc(lane & (int)(RC >> 2)) & 1) != 0;
    const bool hl = (__popc(lane & (int)(R >> 2)) & 1) != 0;
    #pragma unroll
    for (int k = 0; k < 4; ++k) {
        const bool ctrl = cl ^ ((__builtin_popcount((unsigned)k & (RC & 3u)) & 1) != 0);
        const bool hi   = hl ^ ((__builtin_popcount((unsigned)k & (R & 3u)) & 1) != 0);
        const float fr = ctrl ? c : 1.f;
        const float sg = hi ? s : -s;
        const float fi = ctrl ? sg : 0.f;
        cplx n;
        n.re = fr * a[k].re - fi * a[k].im;
        n.im = fr * a[k].im + fi * a[k].re;
        a[k] = n;
    }
}

template <int C>
__device__ __forceinline__ void cycle_ry(cplx a[4], float c, float s, int lane) {
    constexpr M8 F  = (C == 1) ? F1 : (C == 2) ? F2 : F3;
    constexpr M8 Fi = (C == 1) ? F1i : (C == 2) ? F2i : F3i;
    gate_ry<mcol(Fi, 7), F.r[7]>(a, c, s, lane);
    gate_ry<mcol(Fi, 6), F.r[6]>(a, c, s, lane);
    gate_ry<mcol(Fi, 5), F.r[5]>(a, c, s, lane);
    gate_ry<mcol(Fi, 4), F.r[4]>(a, c, s, lane);
    gate_ry<mcol(Fi, 3), F.r[3]>(a, c, s, lane);
    gate_ry<mcol(Fi, 2), F.r[2]>(a, c, s, lane);
    gate_ry<mcol(Fi, 1), F.r[1]>(a, c, s, lane);
    gate_ry<mcol(Fi, 0), F.r[0]>(a, c, s, lane);
}

template <int C>
__device__ __forceinline__ void cycle_diag(cplx a[4], float phw, int lane) {
    constexpr M8 F = (C == 1) ? F1 : (C == 2) ? F2 : F3;
    int hp[8];
    #pragma unroll
    for (int p = 0; p < 8; ++p) hp[p] = __popc(lane & (int)(F.r[p] >> 2)) & 1;
    #pragma unroll
    for (int k = 0; k < 4; ++k) {
        int n = 0;
        #pragma unroll
        for (int p = 0; p < 8; ++p) {
            const int kb = __builtin_popcount(F.r[p] & 3u & (unsigned)k) & 1;
            n += kb ? (1 - hp[p]) : hp[p];
        }
        float sn, cn;
        __sincosf(phw * (float)(n - 4), &sn, &cn);
        cplx v;
        v.re = cn * a[k].re - sn * a[k].im;
        v.im = cn * a[k].im + sn * a[k].re;
        a[k] = v;
    }
}

struct BranchG { float rc[10], rs[10]; Gate u[6]; };

template <int KIND, int PC, int PT>
__device__ __forceinline__ void crot(cplx a[4], float c, float s, int lane) {
    constexpr unsigned X = mcol(F4i, PT), R = F4.r[PT], RC = F4.r[PC];
    if constexpr (KIND == 0)      gate_crx<X, RC>(a, c, s, lane);
    else if constexpr (KIND == 1) gate_cry<X, R, RC>(a, c, s, lane);
    else                          gate_crz<R, RC>(a, c, s, lane);
}

template <int KIND>
__device__ __forceinline__ void run_branch(const BranchG& G, cplx a[4],
                                           int lane, float& o3, float& o7) {
    crot<KIND, 7, 6>(a, G.rc[0], G.rs[0], lane);
    crot<KIND, 5, 4>(a, G.rc[1], G.rs[1], lane);
    crot<KIND, 3, 2>(a, G.rc[2], G.rs[2], lane);
    crot<KIND, 1, 0>(a, G.rc[3], G.rs[3], lane);
    crot<KIND, 6, 5>(a, G.rc[4], G.rs[4], lane);
    crot<KIND, 4, 3>(a, G.rc[5], G.rs[5], lane);
    crot<KIND, 2, 1>(a, G.rc[6], G.rs[6], lane);
    gate_u3<mcol(F4i, 6), F4.r[6]>(a, G.u[0], lane);
    gate_u3<mcol(F4i, 4), F4.r[4]>(a, G.u[1], lane);
    gate_u3<mcol(F4i, 2), F4.r[2]>(a, G.u[2], lane);
    gate_u3<mcol(F4i, 0), F4.r[0]>(a, G.u[3], lane);
    crot<KIND, 6, 4>(a, G.rc[7], G.rs[7], lane);
    crot<KIND, 2, 0>(a, G.rc[8], G.rs[8], lane);
    crot<KIND, 4, 2>(a, G.rc[9], G.rs[9], lane);
    gate_u3<mcol(F4i, 4), F4.r[4]>(a, G.u[4], lane);
    gate_u3<mcol(F4i, 0), F4.r[0]>(a, G.u[5], lane);

    constexpr unsigned R3 = F4.r[4], R7 = F4.r[0];
    const bool h3 = (__popc(lane & (int)(R3 >> 2)) & 1) != 0;
    const bool h7 = (__popc(lane & (int)(R7 >> 2)) & 1) != 0;
    float p3 = 0.f, p7 = 0.f;
    #pragma unroll
    for (int k = 0; k < 4; ++k) {
        const float m = a[k].re * a[k].re + a[k].im * a[k].im;
        const bool s3 = h3 ^ ((__builtin_popcount((unsigned)k & (R3 & 3u)) & 1) != 0);
        const bool s7 = h7 ^ ((__builtin_popcount((unsigned)k & (R7 & 3u)) & 1) != 0);
        p3 += s3 ? -m : m;
        p7 += s7 ? -m : m;
    }
    #pragma unroll
    for (int off = 32; off >= 1; off >>= 1) {
        p3 += shflx(p3, off);
        p7 += shflx(p7, off);
    }
    o3 = p3;
    o7 = p7;
}

// ---------------- K_A: fused base + one branch per wave on the grid ----------------
__global__ void __launch_bounds__(256) k_grid(
    float* __restrict__ feat,
    const float* __restrict__ ax, const float* __restrict__ ay, const float* __restrict__ az,
    const float* __restrict__ u3x, const float* __restrict__ u3y, const float* __restrict__ u3z) {
    __shared__ BranchG gb[3];
    const int t = threadIdx.x;
    if (t < 30) {
        const int br = t / 10, i = t - br * 10;
        const float* ang = (br == 0) ? ax : (br == 1) ? ay : az;
        float s, c;
        __sincosf(0.5f * ang[i], &s, &c);
        gb[br].rc[i] = c;
        gb[br].rs[i] = s;
    } else if (t >= 32 && t < 50) {
        const int idx = t - 32, br = idx / 6, row = idx - br * 6;
        const float* up = (br == 0) ? u3x : (br == 1) ? u3y : u3z;
        const float th = up[row * 3 + 0], ph = up[row * 3 + 1], lm = up[row * 3 + 2];
        float sth, cth; __sincosf(0.5f * th, &sth, &cth);
        float sph, cph; __sincosf(ph, &sph, &cph);
        float slm, clm; __sincosf(lm, &slm, &clm);
        float spl, cpl; __sincosf(ph + lm, &spl, &cpl);
        Gate G;
        G.u00 = {cth, 0.f};
        G.u01 = {-clm * sth, -slm * sth};
        G.u10 = {cph * sth, sph * sth};
        G.u11 = {cpl * cth, spl * cth};
        gb[br].u[row] = G;
    }
    __syncthreads();

    const int W    = blockIdx.x * 4 + (t >> 6);   // 0..3071
    const int br   = W >> 10;
    const int p    = W & 1023;
    const int lane = t & 63;
    const int it = p >> 5, ip = p & 31;
    const float xt = cosf(PI_F * (float)(2 * it + 1) / (2.0f * NCH));
    const float xp = cosf(PI_F * (float)(2 * ip + 1) / (2.0f * NCH));
    const float thv = 0.5f * (xt + 1.f), phv = 0.5f * (xp + 1.f);

    float s, c, sp, cp;
    __sincosf(0.5f * thv, &s, &c);
    __sincosf(0.5f * phv, &sp, &cp);

    cplx a[4];
    {
        float f = 1.f;
        #pragma unroll
        for (int bb = 0; bb < 6; ++bb) f *= ((lane >> bb) & 1) ? s : c;
        const int pl = __popc(lane);
        float e0s, e0c;
        __sincosf(phv * (float)(pl - 4), &e0s, &e0c);
        const float e1c = cp * cp - sp * sp;
        const float e1s = 2.f * sp * cp;
        cplx e0{e0c, e0s};
        cplx e1{e0.re * e1c - e0.im * e1s, e0.re * e1s + e0.im * e1c};
        cplx e2{e1.re * e1c - e1.im * e1s, e1.re * e1s + e1.im * e1c};
        const float cc = c * c, cs = c * s, ss = s * s;
        a[0] = {f * cc * e0.re, f * cc * e0.im};
        a[1] = {f * cs * e1.re, f * cs * e1.im};
        a[2] = {f * cs * e1.re, f * cs * e1.im};
        a[3] = {f * ss * e2.re, f * ss * e2.im};
    }
    cycle_ry<1>(a, c, s, lane);  cycle_diag<1>(a, phv, lane);
    cycle_ry<2>(a, c, s, lane);  cycle_diag<2>(a, phv, lane);
    cycle_ry<3>(a, c, s, lane);  cycle_diag<3>(a, phv, lane);

    float o3, o7;
    if (br == 0)      run_branch<0>(gb[0], a, lane, o3, o7);
    else if (br == 1) run_branch<1>(gb[1], a, lane, o3, o7);
    else              run_branch<2>(gb[2], a, lane, o3, o7);

    if (lane == 0) {
        feat[(br * 2 + 0) * NPTS + p] = o3;
        feat[(br * 2 + 1) * NPTS + p] = o7;
    }
}

// ---------------- K_B: barycentric eval (8-way octant split) + MLP ----------------
// Block = 512 threads = 8 waves per 64 elements (lane = element).
// Wave w computes rows i in [4w, 4w+4) of u^T F v for all 6 features.
__global__ void __launch_bounds__(512) k_eval(
    const float* __restrict__ theta, const float* __restrict__ phi,
    const float* __restrict__ feat,
    const float* __restrict__ W1, const float* __restrict__ b1,
    const float* __restrict__ W2, const float* __restrict__ b2,
    float* __restrict__ out, int B) {
    __shared__ float acc[8][6][64];
    const int t = threadIdx.x, wv = t >> 6, lane = t & 63;
    const int e = blockIdx.x * 64 + lane;
    const bool valid = (e < B);

    const float xt = valid ? (2.f * theta[e] - 1.f) : 0.f;
    const float xp = valid ? (2.f * phi[e]   - 1.f) : 0.f;

    // Full v[32] (compile-time indexed everywhere) + su, sv.
    float v[NCH];
    float su = 0.f, sv = 0.f;
    #pragma unroll
    for (int i = 0; i < NCH; ++i) {
        const float ang = (float)(2 * i + 1) * (PI_F / (2.0f * NCH));
        float sa, ca;
        __sincosf(ang, &sa, &ca);
        const float wi = (i & 1) ? -sa : sa;
        float dt = xt - ca;
        float dp = xp - ca;
        dt = (dt == 0.f) ? 1e-18f : dt;
        dp = (dp == 0.f) ? 1e-18f : dp;
        su += wi / dt;
        v[i] = wi / dp;
        sv += v[i];
    }

    // Own-octant u values -> compile-time-indexed regs (i0 = 4*wv is even,
    // so parity(i0+m) == parity(m); avoids dynamic register-array indexing).
    const int i0 = wv * 4;
    float u4[4];
    #pragma unroll
    for (int m = 0; m < 4; ++m) {
        const float ang = (float)(2 * (i0 + m) + 1) * (PI_F / (2.0f * NCH));
        float sa, ca;
        __sincosf(ang, &sa, &ca);
        const float wi = (m & 1) ? -sa : sa;
        float dt = xt - ca;
        dt = (dt == 0.f) ? 1e-18f : dt;
        u4[m] = wi / dt;
    }

    // Partial u^T F v over this octant's 4 rows, all 6 features.
    #pragma unroll
    for (int f = 0; f < 6; ++f) {
        float s = 0.f;
        #pragma unroll
        for (int m = 0; m < 4; ++m) {
            const float* Fr = feat + f * NPTS + (i0 + m) * NCH;  // wave-uniform
            float row = 0.f;
            #pragma unroll
            for (int j = 0; j < NCH; ++j) row = fmaf(Fr[j], v[j], row);
            s = fmaf(u4[m], row, s);
        }
        acc[wv][f][lane] = s;
    }
    __syncthreads();

    if (wv == 0 && valid) {
        const float inv = 1.f / (su * sv);  // wave 0's own su,sv for element e
        float fv[6];
        #pragma unroll
        for (int f = 0; f < 6; ++f) {
            float s = 0.f;
            #pragma unroll
            for (int w = 0; w < 8; ++w) s += acc[w][f][lane];
            fv[f] = s * inv;
        }
        float o = b2[0];
        #pragma unroll
        for (int j = 0; j < 12; ++j) {
            float h = b1[j];
            #pragma unroll
            for (int k = 0; k < 6; ++k) h = fmaf(W1[j * 6 + k], fv[k], h);
            const float ex = __expf(2.f * h);
            o = fmaf(W2[j], (ex - 1.f) / (ex + 1.f), o);  // tanh
        }
        out[e] = 1.f / (1.f + __expf(-o));
    }
}

extern "C" void kernel_launch(void* const* d_in, const int* in_sizes, int n_in,
                              void* d_out, int out_size, void* d_ws, size_t ws_size,
                              hipStream_t stream) {
    const float* theta = (const float*)d_in[0];
    const float* phi   = (const float*)d_in[1];
    const float* ax    = (const float*)d_in[2];
    const float* ay    = (const float*)d_in[3];
    const float* az    = (const float*)d_in[4];
    const float* u3x   = (const float*)d_in[5];
    const float* u3y   = (const float*)d_in[6];
    const float* u3z   = (const float*)d_in[7];
    const float* W1    = (const float*)d_in[8];
    const float* b1    = (const float*)d_in[9];
    const float* W2    = (const float*)d_in[10];
    const float* b2    = (const float*)d_in[11];
    const int B = in_sizes[0];

    float* feat = (float*)d_ws;  // 6 * 1024 floats = 24 KB

    k_grid<<<3 * NPTS / 4, 256, 0, stream>>>(feat, ax, ay, az, u3x, u3y, u3z);
    k_eval<<<(B + 63) / 64, 512, 0, stream>>>(theta, phi, feat,
                                              W1, b1, W2, b2, (float*)d_out, B);
}